// Round 6
// baseline (474.765 us; speedup 1.0000x reference)
//
#include <hip/hip_runtime.h>
#include <hip/hip_bf16.h>
#include <math.h>

#define B_ 8
#define NQ_ 1024
#define NK_ 1024
#define H_ 8
#define DK_ 64
#define HDK_ 512
#define LOG2E 1.4426950408889634f

typedef _Float16 half8 __attribute__((ext_vector_type(8)));
typedef _Float16 half4 __attribute__((ext_vector_type(4)));
typedef float f32x4 __attribute__((ext_vector_type(4)));

// ---------------------------------------------------------------------------
// Detect whether attention_mask is stored as 1-byte or 4-byte elements.
__global__ void detect_mask_kernel(const unsigned int* __restrict__ w, int nwords,
                                   int* __restrict__ flag) {
  __shared__ int s;
  if (threadIdx.x == 0) s = 0;
  __syncthreads();
  int bad = 0;
  for (int i = threadIdx.x; i < nwords; i += blockDim.x) {
    unsigned int v = w[i];
    if (v > 1u && v != 0x3F800000u) bad = 1;
  }
  if (bad) atomicOr(&s, 1);
  __syncthreads();
  if (threadIdx.x == 0) *flag = s;  // 1 => bytes, 0 => 4-byte words
}

// ---------------------------------------------------------------------------
// Transpose+cast 512x512 weight matrices via LDS tiles: Wt[n][k] = W[k][n]
__global__ __launch_bounds__(256)
void wtrans_kernel(const float* __restrict__ w0, const float* __restrict__ w1,
                   const float* __restrict__ w2, const float* __restrict__ w3,
                   _Float16* __restrict__ t0, _Float16* __restrict__ t1,
                   _Float16* __restrict__ t2, _Float16* __restrict__ t3) {
  __shared__ float tile[64][65];
  const float* W;
  _Float16* T;
  switch (blockIdx.y) {
    case 0: W = w0; T = t0; break;
    case 1: W = w1; T = t1; break;
    case 2: W = w2; T = t2; break;
    default: W = w3; T = t3; break;
  }
  const int t = blockIdx.x;              // 64 tiles
  const int k0 = (t >> 3) * 64, n0 = (t & 7) * 64;
  const int tid = threadIdx.x;
  const int r = tid >> 4, c4 = (tid & 15) * 4;
#pragma unroll
  for (int i = 0; i < 4; ++i) {
    const int kk = r + i * 16;
    float4 v = *(const float4*)(W + (size_t)(k0 + kk) * 512 + n0 + c4);
    tile[kk][c4 + 0] = v.x;
    tile[kk][c4 + 1] = v.y;
    tile[kk][c4 + 2] = v.z;
    tile[kk][c4 + 3] = v.w;
  }
  __syncthreads();
#pragma unroll
  for (int i = 0; i < 4; ++i) {
    const int nn = r + i * 16;
    half4 h;
#pragma unroll
    for (int j = 0; j < 4; ++j) h[j] = (_Float16)tile[c4 + j][nn];
    *(half4*)(T + (size_t)(n0 + nn) * 512 + k0 + c4) = h;
  }
}

// ---------------------------------------------------------------------------
// 8192x512x512 fp16 MFMA GEMM. A is f32 (cast in staging) except mode 3 (f16).
__global__ __launch_bounds__(256)
void gemm_kernel(const float* __restrict__ A32, const _Float16* __restrict__ A16,
                 const _Float16* __restrict__ Bt, const float* __restrict__ bias,
                 const float* __restrict__ mem, const float* __restrict__ Wmm,
                 const float* __restrict__ bmm, void* __restrict__ outp,
                 const int mode) {
  __shared__ _Float16 As[128 * 32];
  __shared__ _Float16 Bs[128 * 32];
  const int tid = threadIdx.x;
  const int lane = tid & 63, wave = tid >> 6;
  const int wr = wave >> 1, wc = wave & 1;
  const int l15 = lane & 15, l4 = lane >> 4;
  const int row0 = blockIdx.x * 128, col0 = blockIdx.y * 128;
  const int srow = tid >> 1;
  const int sc0 = (tid & 1) * 2;

  f32x4 acc[4][4] = {};

  for (int k0 = 0; k0 < 512; k0 += 32) {
    __syncthreads();
    const _Float16* sb = Bt + (size_t)(col0 + srow) * 512 + k0;
#pragma unroll
    for (int c = 0; c < 2; ++c) {
      int ci = sc0 + c;
      half8 ha;
      if (mode == 3) {
        ha = *(const half8*)(A16 + (size_t)(row0 + srow) * 512 + k0 + ci * 8);
      } else {
        const float* s = A32 + (size_t)(row0 + srow) * 512 + k0 + ci * 8;
        float4 x = *(const float4*)s;
        float4 y = *(const float4*)(s + 4);
        ha[0] = (_Float16)x.x; ha[1] = (_Float16)x.y;
        ha[2] = (_Float16)x.z; ha[3] = (_Float16)x.w;
        ha[4] = (_Float16)y.x; ha[5] = (_Float16)y.y;
        ha[6] = (_Float16)y.z; ha[7] = (_Float16)y.w;
      }
      float4 vb = *(const float4*)(sb + ci * 8);
      int cd = ci ^ (srow & 3);
      *(half8*)((char*)As + srow * 64 + (cd << 4)) = ha;
      *(float4*)((char*)Bs + srow * 64 + (cd << 4)) = vb;
    }
    __syncthreads();
    half8 af[4], bf[4];
#pragma unroll
    for (int mi = 0; mi < 4; ++mi) {
      int r = wr * 64 + mi * 16 + l15;
      af[mi] = *(half8*)((char*)As + r * 64 + ((l4 ^ (r & 3)) << 4));
    }
#pragma unroll
    for (int ni = 0; ni < 4; ++ni) {
      int r = wc * 64 + ni * 16 + l15;
      bf[ni] = *(half8*)((char*)Bs + r * 64 + ((l4 ^ (r & 3)) << 4));
    }
#pragma unroll
    for (int mi = 0; mi < 4; ++mi)
#pragma unroll
      for (int ni = 0; ni < 4; ++ni)
        acc[mi][ni] =
            __builtin_amdgcn_mfma_f32_16x16x32_f16(af[mi], bf[ni], acc[mi][ni], 0, 0, 0);
  }

#pragma unroll
  for (int mi = 0; mi < 4; ++mi) {
#pragma unroll
    for (int ni = 0; ni < 4; ++ni) {
      const int gc = col0 + wc * 64 + ni * 16 + l15;
      const float bi = bias[gc];
      const int h = gc >> 6, d = gc & 63;
#pragma unroll
      for (int reg = 0; reg < 4; ++reg) {
        const int gr = row0 + wr * 64 + mi * 16 + l4 * 4 + reg;
        float val = acc[mi][ni][reg] + bi;
        if (mode == 3) {
          ((float*)outp)[(size_t)gr * 512 + gc] = val;
        } else if (mode == 0) {
          const int b = gr >> 10, n = gr & 1023;
          ((_Float16*)outp)[((size_t)(b * 8 + h) * 1024 + n) * 64 + d] =
              (_Float16)(val * (LOG2E / 8.0f));
        } else {
          const int b = gr >> 10, n = gr & 1023;
          float mmv = fmaf(mem[gr], Wmm[gc], bmm[gc]);
          float g = val * mmv;
          if (mode == 1)
            ((_Float16*)outp)[((size_t)(b * 8 + h) * 1024 + n) * 64 + d] = (_Float16)g;
          else
            ((_Float16*)outp)[((size_t)(b * 8 + h) * 64 + d) * 1024 + n] = (_Float16)g;
        }
      }
    }
  }
}

// ---------------------------------------------------------------------------
// Flash attention, swapped-operand QK^T. BARRIER-FREE: K/V fragments read
// directly from global (L2-resident: 256 KB per head, head pinned to one XCD
// by the block swizzle). Only per-wave P staging uses LDS (8 KB/block,
// same-wave write->read, no sync needed). Waves run fully independently so
// global loads stay continuously in flight. w/g/mask prefetched 1 tile ahead.
__global__ __launch_bounds__(256, 2)
void attn_kernel(const _Float16* __restrict__ Qp, const _Float16* __restrict__ Kg,
                 const _Float16* __restrict__ Vgt, const float* __restrict__ attw,
                 const float* __restrict__ geom, const void* __restrict__ maskp,
                 const int* __restrict__ flagp, _Float16* __restrict__ Ocat) {
  __shared__ _Float16 Ps[4][16 * 64];  // per-wave P, [q][k], swizzled

  const int tid = threadIdx.x;
  const int lane = tid & 63, wave = tid >> 6;
  const int l15 = lane & 15, l4 = lane >> 4;
  // XCD swizzle: bid&63 = (b,h) -> head h pinned to XCD h; K/V L2-resident
  const int bid = blockIdx.x;
  const int qt = bid >> 6;
  const int g = bid & 63;
  const int h = g & 7, b = g >> 3;
  const int bh = b * H_ + h;
  const int qb = qt * 64 + wave * 16;
  const int kq = qb + l15;  // this lane's q row
  const int maskBytes = *flagp;
  const unsigned char* m8 = (const unsigned char*)maskp;
  const int* m32 = (const int*)maskp;

  // Q as B-operand: B[col=l15=q][kk=d]
  half8 aq[2];
  {
    const _Float16* qsrc = Qp + ((size_t)bh * NQ_ + kq) * DK_;
#pragma unroll
    for (int s = 0; s < 2; ++s) aq[s] = *(const half8*)(qsrc + s * 32 + l4 * 8);
  }

  f32x4 fo[4] = {};  // O accum: row=q-local(l4*4+reg), col=d(c*16+l15)
  float mrun = -INFINITY, lrun = 0.f;

  const _Float16* Kbase = Kg + (size_t)bh * NK_ * DK_;
  const _Float16* Vbase = Vgt + (size_t)bh * DK_ * NK_;
  const size_t wgBase = ((size_t)bh << 20) + (size_t)kq * NK_ + l4 * 4;

  // ---- single w/g/mask register set (mask packed: bit c*4+reg)
  float4 wv[4], gv[4];
  unsigned mk;
  auto loadWG = [&](int kt) {
    const size_t base = wgBase + (size_t)kt * 64;
    unsigned m = 0;
#pragma unroll
    for (int c = 0; c < 4; ++c) {
      wv[c] = *(const float4*)(attw + base + c * 16);
      gv[c] = *(const float4*)(geom + base + c * 16);
      if (maskBytes) {
        unsigned v = *(const unsigned*)(m8 + base + c * 16);
        m |= (((v & 0xffu) ? 1u : 0u) | ((v & 0xff00u) ? 2u : 0u) |
              ((v & 0xff0000u) ? 4u : 0u) | ((v & 0xff000000u) ? 8u : 0u)) << (c * 4);
      } else {
        int4 v = *(const int4*)(m32 + base + c * 16);
        m |= ((v.x ? 1u : 0u) | (v.y ? 2u : 0u) | (v.z ? 4u : 0u) | (v.w ? 8u : 0u))
             << (c * 4);
      }
    }
    mk = m;
  };

  loadWG(0);

  for (int kt = 0; kt < 16; ++kt) {
    // ---- QK^T swapped: A = K rows (k) loaded straight from L2, B = Q
    f32x4 sf[4];
    __builtin_amdgcn_s_setprio(1);
#pragma unroll
    for (int c = 0; c < 4; ++c) {
      sf[c] = (f32x4){0.f, 0.f, 0.f, 0.f};
#pragma unroll
      for (int s = 0; s < 2; ++s) {
        const _Float16* kp =
            Kbase + (size_t)(kt * 64 + c * 16 + l15) * DK_ + s * 32 + l4 * 8;
        half8 ak = *(const half8*)kp;
        sf[c] = __builtin_amdgcn_mfma_f32_16x16x32_f16(ak, aq[s], sf[c], 0, 0, 0);
      }
    }
    __builtin_amdgcn_s_setprio(0);

    // ---- scores consume wv/gv/mk: k = kt*64 + c*16 + l4*4 + reg
#pragma unroll
    for (int c = 0; c < 4; ++c) {
#pragma unroll
      for (int reg = 0; reg < 4; ++reg) {
        float t;
        if ((mk >> (c * 4 + reg)) & 1u)
          t = -INFINITY;
        else
          t = fmaf(sf[c][reg], wv[c][reg], __log2f(fmaxf(gv[c][reg], 1e-6f)));
        sf[c][reg] = t;
      }
    }

    // wg registers now dead -> issue next tile's loads into them
    if (kt + 1 < 16) loadWG(kt + 1);

    // ---- online softmax; row q lives in lanes {l15, +16, +32, +48}
    float mx = -INFINITY;
#pragma unroll
    for (int c = 0; c < 4; ++c)
#pragma unroll
      for (int reg = 0; reg < 4; ++reg) mx = fmaxf(mx, sf[c][reg]);
    mx = fmaxf(mx, __shfl_xor(mx, 16));
    mx = fmaxf(mx, __shfl_xor(mx, 32));
    float mn = fmaxf(mrun, mx);
    float sc = (mrun == -INFINITY) ? 0.f : exp2f(mrun - mn);
    mrun = mn;
    lrun *= sc;

    float scq[4];
#pragma unroll
    for (int reg = 0; reg < 4; ++reg) scq[reg] = __shfl(sc, l4 * 4 + reg);
#pragma unroll
    for (int c = 0; c < 4; ++c)
#pragma unroll
      for (int reg = 0; reg < 4; ++reg) fo[c][reg] *= scq[reg];

    float rs = 0.f;
#pragma unroll
    for (int c = 0; c < 4; ++c)
#pragma unroll
      for (int reg = 0; reg < 4; ++reg) {
        float t = sf[c][reg];
        float p = (t == -INFINITY) ? 0.f : exp2f(t - mrun);
        sf[c][reg] = p;
        rs += p;
      }
    rs += __shfl_xor(rs, 16);
    rs += __shfl_xor(rs, 32);
    lrun += rs;

    // ---- P -> per-wave LDS [q=l15][k], swizzled (same-wave, no barrier)
    char* pw = (char*)&Ps[wave][0];
#pragma unroll
    for (int c = 0; c < 4; ++c) {
      half4 hp;
#pragma unroll
      for (int reg = 0; reg < 4; ++reg) hp[reg] = (_Float16)sf[c][reg];
      int ci = c * 2 + (l4 >> 1);
      *(half4*)(pw + l15 * 128 + ((ci ^ (l15 & 7)) << 4) + (l4 & 1) * 8) = hp;
    }

    // ---- PV: A = P[q][k] from LDS, B = V[d][k] straight from L2
    __builtin_amdgcn_s_setprio(1);
#pragma unroll
    for (int s4 = 0; s4 < 2; ++s4) {
      half8 pa = *(half8*)(pw + l15 * 128 + (((s4 * 4 + l4) ^ (l15 & 7)) << 4));
#pragma unroll
      for (int c = 0; c < 4; ++c) {
        const _Float16* vp =
            Vbase + (size_t)(c * 16 + l15) * NK_ + kt * 64 + s4 * 32 + l4 * 8;
        half8 bv = *(const half8*)vp;
        fo[c] = __builtin_amdgcn_mfma_f32_16x16x32_f16(pa, bv, fo[c], 0, 0, 0);
      }
    }
    __builtin_amdgcn_s_setprio(0);
  }

  // normalize + store; fo rows are q-local = l4*4+reg -> shuffle lrun
  float rinv[4];
#pragma unroll
  for (int reg = 0; reg < 4; ++reg) rinv[reg] = 1.0f / __shfl(lrun, l4 * 4 + reg);
#pragma unroll
  for (int c = 0; c < 4; ++c) {
    const int d = c * 16 + l15;
#pragma unroll
    for (int reg = 0; reg < 4; ++reg) {
      const int qg = qb + l4 * 4 + reg;
      Ocat[((size_t)b * NQ_ + qg) * HDK_ + h * DK_ + d] =
          (_Float16)(fo[c][reg] * rinv[reg]);
    }
  }
}

// ---------------------------------------------------------------------------
extern "C" void kernel_launch(void* const* d_in, const int* in_sizes, int n_in,
                              void* d_out, int out_size, void* d_ws, size_t ws_size,
                              hipStream_t stream) {
  (void)in_sizes; (void)n_in; (void)out_size; (void)ws_size;
  const float* queries = (const float*)d_in[0];
  const float* keys    = (const float*)d_in[1];
  const float* values  = (const float*)d_in[2];
  const void*  maskp   = d_in[3];
  const float* attw    = (const float*)d_in[4];
  const float* memo    = (const float*)d_in[5];
  const float* geom    = (const float*)d_in[6];
  const float* Wq = (const float*)d_in[7];
  const float* bq = (const float*)d_in[8];
  const float* Wk = (const float*)d_in[9];
  const float* bk = (const float*)d_in[10];
  const float* Wv = (const float*)d_in[11];
  const float* bv = (const float*)d_in[12];
  const float* Wmm = (const float*)d_in[13];
  const float* bmm = (const float*)d_in[14];
  const float* Wo = (const float*)d_in[15];
  const float* bo = (const float*)d_in[16];

  char* ws = (char*)d_ws;
  size_t off = 0;
  auto alloc = [&](size_t bytes) {
    char* p = ws + off;
    off += (bytes + 255) & ~(size_t)255;
    return p;
  };
  const size_t MAT = (size_t)8192 * 512 * 2;  // 8 MiB fp16
  int* flag = (int*)alloc(256);
  _Float16* Wtq = (_Float16*)alloc((size_t)512 * 512 * 2);
  _Float16* Wtk = (_Float16*)alloc((size_t)512 * 512 * 2);
  _Float16* Wtv = (_Float16*)alloc((size_t)512 * 512 * 2);
  _Float16* Wto = (_Float16*)alloc((size_t)512 * 512 * 2);
  _Float16* Qp   = (_Float16*)alloc(MAT);
  _Float16* Kgp  = (_Float16*)alloc(MAT);
  _Float16* Vgtp = (_Float16*)alloc(MAT);
  _Float16* Ocat = (_Float16*)alloc(MAT);

  detect_mask_kernel<<<1, 256, 0, stream>>>((const unsigned int*)maskp, 4096, flag);
  wtrans_kernel<<<dim3(64, 4), 256, 0, stream>>>(Wq, Wk, Wv, Wo, Wtq, Wtk, Wtv, Wto);

  dim3 ggrid(64, 4);
  gemm_kernel<<<ggrid, 256, 0, stream>>>(queries, nullptr, Wtq, bq, nullptr, nullptr,
                                         nullptr, Qp, 0);
  gemm_kernel<<<ggrid, 256, 0, stream>>>(keys, nullptr, Wtk, bk, memo, Wmm, bmm, Kgp, 1);
  gemm_kernel<<<ggrid, 256, 0, stream>>>(values, nullptr, Wtv, bv, memo, Wmm, bmm,
                                         Vgtp, 2);

  attn_kernel<<<1024, 256, 0, stream>>>(Qp, Kgp, Vgtp, attw, geom, maskp, flag, Ocat);

  gemm_kernel<<<ggrid, 256, 0, stream>>>(nullptr, Ocat, Wto, bo, nullptr, nullptr,
                                         nullptr, d_out, 3);
}

// Round 7
// 337.660 us; speedup vs baseline: 1.4060x; 1.4060x over previous
//
#include <hip/hip_runtime.h>
#include <hip/hip_bf16.h>
#include <math.h>

#define B_ 8
#define NQ_ 1024
#define NK_ 1024
#define H_ 8
#define DK_ 64
#define HDK_ 512
#define LOG2E 1.4426950408889634f

typedef _Float16 half8 __attribute__((ext_vector_type(8)));
typedef _Float16 half4 __attribute__((ext_vector_type(4)));
typedef float f32x4 __attribute__((ext_vector_type(4)));

// ---------------------------------------------------------------------------
// Detect whether attention_mask is stored as 1-byte or 4-byte elements.
__global__ void detect_mask_kernel(const unsigned int* __restrict__ w, int nwords,
                                   int* __restrict__ flag) {
  __shared__ int s;
  if (threadIdx.x == 0) s = 0;
  __syncthreads();
  int bad = 0;
  for (int i = threadIdx.x; i < nwords; i += blockDim.x) {
    unsigned int v = w[i];
    if (v > 1u && v != 0x3F800000u) bad = 1;
  }
  if (bad) atomicOr(&s, 1);
  __syncthreads();
  if (threadIdx.x == 0) *flag = s;  // 1 => bytes, 0 => 4-byte words
}

// ---------------------------------------------------------------------------
// Transpose+cast 512x512 weight matrices via LDS tiles: Wt[n][k] = W[k][n]
__global__ __launch_bounds__(256)
void wtrans_kernel(const float* __restrict__ w0, const float* __restrict__ w1,
                   const float* __restrict__ w2, const float* __restrict__ w3,
                   _Float16* __restrict__ t0, _Float16* __restrict__ t1,
                   _Float16* __restrict__ t2, _Float16* __restrict__ t3) {
  __shared__ float tile[64][65];
  const float* W;
  _Float16* T;
  switch (blockIdx.y) {
    case 0: W = w0; T = t0; break;
    case 1: W = w1; T = t1; break;
    case 2: W = w2; T = t2; break;
    default: W = w3; T = t3; break;
  }
  const int t = blockIdx.x;              // 64 tiles
  const int k0 = (t >> 3) * 64, n0 = (t & 7) * 64;
  const int tid = threadIdx.x;
  const int r = tid >> 4, c4 = (tid & 15) * 4;
#pragma unroll
  for (int i = 0; i < 4; ++i) {
    const int kk = r + i * 16;
    float4 v = *(const float4*)(W + (size_t)(k0 + kk) * 512 + n0 + c4);
    tile[kk][c4 + 0] = v.x;
    tile[kk][c4 + 1] = v.y;
    tile[kk][c4 + 2] = v.z;
    tile[kk][c4 + 3] = v.w;
  }
  __syncthreads();
#pragma unroll
  for (int i = 0; i < 4; ++i) {
    const int nn = r + i * 16;
    half4 h;
#pragma unroll
    for (int j = 0; j < 4; ++j) h[j] = (_Float16)tile[c4 + j][nn];
    *(half4*)(T + (size_t)(n0 + nn) * 512 + k0 + c4) = h;
  }
}

// ---------------------------------------------------------------------------
// 8192x512x512 fp16 MFMA GEMM. A is f32 (cast in staging) except mode 3 (f16).
__global__ __launch_bounds__(256)
void gemm_kernel(const float* __restrict__ A32, const _Float16* __restrict__ A16,
                 const _Float16* __restrict__ Bt, const float* __restrict__ bias,
                 const float* __restrict__ mem, const float* __restrict__ Wmm,
                 const float* __restrict__ bmm, void* __restrict__ outp,
                 const int mode) {
  __shared__ _Float16 As[128 * 32];
  __shared__ _Float16 Bs[128 * 32];
  const int tid = threadIdx.x;
  const int lane = tid & 63, wave = tid >> 6;
  const int wr = wave >> 1, wc = wave & 1;
  const int l15 = lane & 15, l4 = lane >> 4;
  const int row0 = blockIdx.x * 128, col0 = blockIdx.y * 128;
  const int srow = tid >> 1;
  const int sc0 = (tid & 1) * 2;

  f32x4 acc[4][4] = {};

  for (int k0 = 0; k0 < 512; k0 += 32) {
    __syncthreads();
    const _Float16* sb = Bt + (size_t)(col0 + srow) * 512 + k0;
#pragma unroll
    for (int c = 0; c < 2; ++c) {
      int ci = sc0 + c;
      half8 ha;
      if (mode == 3) {
        ha = *(const half8*)(A16 + (size_t)(row0 + srow) * 512 + k0 + ci * 8);
      } else {
        const float* s = A32 + (size_t)(row0 + srow) * 512 + k0 + ci * 8;
        float4 x = *(const float4*)s;
        float4 y = *(const float4*)(s + 4);
        ha[0] = (_Float16)x.x; ha[1] = (_Float16)x.y;
        ha[2] = (_Float16)x.z; ha[3] = (_Float16)x.w;
        ha[4] = (_Float16)y.x; ha[5] = (_Float16)y.y;
        ha[6] = (_Float16)y.z; ha[7] = (_Float16)y.w;
      }
      float4 vb = *(const float4*)(sb + ci * 8);
      int cd = ci ^ (srow & 3);
      *(half8*)((char*)As + srow * 64 + (cd << 4)) = ha;
      *(float4*)((char*)Bs + srow * 64 + (cd << 4)) = vb;
    }
    __syncthreads();
    half8 af[4], bf[4];
#pragma unroll
    for (int mi = 0; mi < 4; ++mi) {
      int r = wr * 64 + mi * 16 + l15;
      af[mi] = *(half8*)((char*)As + r * 64 + ((l4 ^ (r & 3)) << 4));
    }
#pragma unroll
    for (int ni = 0; ni < 4; ++ni) {
      int r = wc * 64 + ni * 16 + l15;
      bf[ni] = *(half8*)((char*)Bs + r * 64 + ((l4 ^ (r & 3)) << 4));
    }
#pragma unroll
    for (int mi = 0; mi < 4; ++mi)
#pragma unroll
      for (int ni = 0; ni < 4; ++ni)
        acc[mi][ni] =
            __builtin_amdgcn_mfma_f32_16x16x32_f16(af[mi], bf[ni], acc[mi][ni], 0, 0, 0);
  }

#pragma unroll
  for (int mi = 0; mi < 4; ++mi) {
#pragma unroll
    for (int ni = 0; ni < 4; ++ni) {
      const int gc = col0 + wc * 64 + ni * 16 + l15;
      const float bi = bias[gc];
      const int h = gc >> 6, d = gc & 63;
#pragma unroll
      for (int reg = 0; reg < 4; ++reg) {
        const int gr = row0 + wr * 64 + mi * 16 + l4 * 4 + reg;
        float val = acc[mi][ni][reg] + bi;
        if (mode == 3) {
          ((float*)outp)[(size_t)gr * 512 + gc] = val;
        } else if (mode == 0) {
          const int b = gr >> 10, n = gr & 1023;
          ((_Float16*)outp)[((size_t)(b * 8 + h) * 1024 + n) * 64 + d] =
              (_Float16)(val * (LOG2E / 8.0f));
        } else {
          const int b = gr >> 10, n = gr & 1023;
          float mmv = fmaf(mem[gr], Wmm[gc], bmm[gc]);
          float g = val * mmv;
          if (mode == 1)
            ((_Float16*)outp)[((size_t)(b * 8 + h) * 1024 + n) * 64 + d] = (_Float16)g;
          else
            ((_Float16*)outp)[((size_t)(b * 8 + h) * 64 + d) * 1024 + n] = (_Float16)g;
        }
      }
    }
  }
}

// ---------------------------------------------------------------------------
// Flash attention, swapped-operand QK^T. Double-buffered K/V staged via
// global_load_lds at iteration top. T4 counted-vmcnt schedule: raw s_barrier
// with `s_waitcnt vmcnt(12)` so only the 4 stage loads drain at the barrier;
// the 12 w/g/mask stream loads stay in flight ACROSS the barrier with a full
// iteration of latency cover (compiler auto-waits vmcnt(4) before scores).
__global__ __launch_bounds__(256, 2)
void attn_kernel(const _Float16* __restrict__ Qp, const _Float16* __restrict__ Kg,
                 const _Float16* __restrict__ Vgt, const float* __restrict__ attw,
                 const float* __restrict__ geom, const void* __restrict__ maskp,
                 const int* __restrict__ flagp, _Float16* __restrict__ Ocat) {
  __shared__ _Float16 Kbuf[2][64 * 64];  // [k][d], 128B rows, XOR swizzled
  __shared__ _Float16 Vbuf[2][64 * 64];  // [d][k], 128B rows, XOR swizzled
  __shared__ _Float16 Ps[4][16 * 64];    // per-wave P, [q][k], swizzled

  const int tid = threadIdx.x;
  const int lane = tid & 63, wave = tid >> 6;
  const int l15 = lane & 15, l4 = lane >> 4;
  // XCD swizzle: bid&63 = (b,h) -> head h pinned to XCD h; K/V L2-resident
  const int bid = blockIdx.x;
  const int qt = bid >> 6;
  const int g = bid & 63;
  const int h = g & 7, b = g >> 3;
  const int bh = b * H_ + h;
  const int qb = qt * 64 + wave * 16;
  const int kq = qb + l15;  // this lane's q row
  const int maskBytes = *flagp;
  const unsigned char* m8 = (const unsigned char*)maskp;
  const int* m32 = (const int*)maskp;

  // Q as B-operand: B[col=l15=q][kk=d]
  half8 aq[2];
  {
    const _Float16* qsrc = Qp + ((size_t)bh * NQ_ + kq) * DK_;
#pragma unroll
    for (int s = 0; s < 2; ++s) aq[s] = *(const half8*)(qsrc + s * 32 + l4 * 8);
  }

  f32x4 fo[4] = {};  // O accum: row=q-local(l4*4+reg), col=d(c*16+l15)
  float mrun = -INFINITY, lrun = 0.f;

  const size_t wgBase = ((size_t)bh << 20) + (size_t)kq * NK_ + l4 * 4;

  // ---- direct global->LDS staging, pre-swizzled source (involution XOR)
  const int srL = lane >> 3;   // sub-row within 8-row issue
  const int sci = lane & 7;    // physical 16B chunk
  auto stageKV = [&](int kt, int sel) {
    const char* kgb = (const char*)(Kg + ((size_t)bh * NK_ + kt * 64) * DK_);
    const char* vgb = (const char*)(Vgt + (size_t)bh * DK_ * NK_ + kt * 64);
#pragma unroll
    for (int i = 0; i < 2; ++i) {
      const int rbase = wave * 16 + i * 8;
      const int r = rbase + srL;
      const char* src = kgb + (size_t)r * 128 + ((sci ^ (r & 7)) << 4);
      __builtin_amdgcn_global_load_lds(src, (char*)&Kbuf[sel][0] + rbase * 128, 16, 0, 0);
    }
#pragma unroll
    for (int i = 0; i < 2; ++i) {
      const int rbase = wave * 16 + i * 8;
      const int r = rbase + srL;
      const char* src = vgb + (size_t)r * (NK_ * 2) + ((sci ^ (r & 7)) << 4);
      __builtin_amdgcn_global_load_lds(src, (char*)&Vbuf[sel][0] + rbase * 128, 16, 0, 0);
    }
  };

  // ---- single w/g/mask register set (mask packed: bit c*4+reg) = 12 vmem
  float4 wv[4], gv[4];
  unsigned mk;
  auto loadWG = [&](int kt) {
    const size_t base = wgBase + (size_t)kt * 64;
    unsigned m = 0;
#pragma unroll
    for (int c = 0; c < 4; ++c) {
      wv[c] = *(const float4*)(attw + base + c * 16);
      gv[c] = *(const float4*)(geom + base + c * 16);
      if (maskBytes) {
        unsigned v = *(const unsigned*)(m8 + base + c * 16);
        m |= (((v & 0xffu) ? 1u : 0u) | ((v & 0xff00u) ? 2u : 0u) |
              ((v & 0xff0000u) ? 4u : 0u) | ((v & 0xff000000u) ? 8u : 0u)) << (c * 4);
      } else {
        int4 v = *(const int4*)(m32 + base + c * 16);
        m |= ((v.x ? 1u : 0u) | (v.y ? 2u : 0u) | (v.z ? 4u : 0u) | (v.w ? 8u : 0u))
             << (c * 4);
      }
    }
    mk = m;
  };

  // prologue: stage tile 0, load wg 0, full drain, barrier
  stageKV(0, 0);
  loadWG(0);
  asm volatile("s_waitcnt vmcnt(0)" ::: "memory");
  __builtin_amdgcn_s_barrier();
  __builtin_amdgcn_sched_barrier(0);

#pragma unroll 2
  for (int kt = 0; kt < 16; ++kt) {
    const int sel = kt & 1;
    if (kt + 1 < 16) {
      stageKV(kt + 1, sel ^ 1);  // 4 gload_lds, issued FIRST (oldest in queue)
      __builtin_amdgcn_sched_barrier(0);
    }

    const char* Kb = (const char*)&Kbuf[sel][0];
    const char* Vb = (const char*)&Vbuf[sel][0];

    // ---- QK^T swapped: A = K rows (k), B = Q cols (q)
    f32x4 sf[4];
    __builtin_amdgcn_s_setprio(1);
#pragma unroll
    for (int c = 0; c < 4; ++c) {
      sf[c] = (f32x4){0.f, 0.f, 0.f, 0.f};
#pragma unroll
      for (int s = 0; s < 2; ++s) {
        int r = c * 16 + l15;
        half8 ak = *(half8*)(Kb + r * 128 + (((s * 4 + l4) ^ (r & 7)) << 4));
        sf[c] = __builtin_amdgcn_mfma_f32_16x16x32_f16(ak, aq[s], sf[c], 0, 0, 0);
      }
    }
    __builtin_amdgcn_s_setprio(0);

    // ---- scores consume wv/gv/mk (compiler auto-waits vmcnt, keeps stage)
#pragma unroll
    for (int c = 0; c < 4; ++c) {
#pragma unroll
      for (int reg = 0; reg < 4; ++reg) {
        float t;
        if ((mk >> (c * 4 + reg)) & 1u)
          t = -INFINITY;
        else
          t = fmaf(sf[c][reg], wv[c][reg], __log2f(fmaxf(gv[c][reg], 1e-6f)));
        sf[c][reg] = t;
      }
    }

    // wg registers now dead -> issue next tile's 12 stream loads into them
    if (kt + 1 < 16) loadWG(kt + 1);

    // ---- online softmax; row q lives in lanes {l15, +16, +32, +48}
    float mx = -INFINITY;
#pragma unroll
    for (int c = 0; c < 4; ++c)
#pragma unroll
      for (int reg = 0; reg < 4; ++reg) mx = fmaxf(mx, sf[c][reg]);
    mx = fmaxf(mx, __shfl_xor(mx, 16));
    mx = fmaxf(mx, __shfl_xor(mx, 32));
    float mn = fmaxf(mrun, mx);
    float sc = (mrun == -INFINITY) ? 0.f : exp2f(mrun - mn);
    mrun = mn;
    lrun *= sc;

    float scq[4];
#pragma unroll
    for (int reg = 0; reg < 4; ++reg) scq[reg] = __shfl(sc, l4 * 4 + reg);
#pragma unroll
    for (int c = 0; c < 4; ++c)
#pragma unroll
      for (int reg = 0; reg < 4; ++reg) fo[c][reg] *= scq[reg];

    float rs = 0.f;
#pragma unroll
    for (int c = 0; c < 4; ++c)
#pragma unroll
      for (int reg = 0; reg < 4; ++reg) {
        float t = sf[c][reg];
        float p = (t == -INFINITY) ? 0.f : exp2f(t - mrun);
        sf[c][reg] = p;
        rs += p;
      }
    rs += __shfl_xor(rs, 16);
    rs += __shfl_xor(rs, 32);
    lrun += rs;

    // ---- P -> per-wave LDS [q=l15][k], swizzled (same-wave, no barrier)
    char* pw = (char*)&Ps[wave][0];
#pragma unroll
    for (int c = 0; c < 4; ++c) {
      half4 hp;
#pragma unroll
      for (int reg = 0; reg < 4; ++reg) hp[reg] = (_Float16)sf[c][reg];
      int ci = c * 2 + (l4 >> 1);
      *(half4*)(pw + l15 * 128 + ((ci ^ (l15 & 7)) << 4) + (l4 & 1) * 8) = hp;
    }

    // ---- PV: A = P[q][k], B = Vs[d][k]
    __builtin_amdgcn_s_setprio(1);
#pragma unroll
    for (int s4 = 0; s4 < 2; ++s4) {
      half8 pa = *(half8*)(pw + l15 * 128 + (((s4 * 4 + l4) ^ (l15 & 7)) << 4));
#pragma unroll
      for (int c = 0; c < 4; ++c) {
        int rd = c * 16 + l15;
        half8 bv = *(half8*)(Vb + rd * 128 + (((s4 * 4 + l4) ^ (rd & 7)) << 4));
        fo[c] = __builtin_amdgcn_mfma_f32_16x16x32_f16(pa, bv, fo[c], 0, 0, 0);
      }
    }
    __builtin_amdgcn_s_setprio(0);

    // ---- T4: drain ONLY the 4 stage loads; 12 wg loads cross the barrier
    if (kt + 1 < 16) {
      asm volatile("s_waitcnt vmcnt(12)" ::: "memory");
      __builtin_amdgcn_s_barrier();
      __builtin_amdgcn_sched_barrier(0);
    }
  }

  // normalize + store; fo rows are q-local = l4*4+reg -> shuffle lrun
  float rinv[4];
#pragma unroll
  for (int reg = 0; reg < 4; ++reg) rinv[reg] = 1.0f / __shfl(lrun, l4 * 4 + reg);
#pragma unroll
  for (int c = 0; c < 4; ++c) {
    const int d = c * 16 + l15;
#pragma unroll
    for (int reg = 0; reg < 4; ++reg) {
      const int qg = qb + l4 * 4 + reg;
      Ocat[((size_t)b * NQ_ + qg) * HDK_ + h * DK_ + d] =
          (_Float16)(fo[c][reg] * rinv[reg]);
    }
  }
}

// ---------------------------------------------------------------------------
extern "C" void kernel_launch(void* const* d_in, const int* in_sizes, int n_in,
                              void* d_out, int out_size, void* d_ws, size_t ws_size,
                              hipStream_t stream) {
  (void)in_sizes; (void)n_in; (void)out_size; (void)ws_size;
  const float* queries = (const float*)d_in[0];
  const float* keys    = (const float*)d_in[1];
  const float* values  = (const float*)d_in[2];
  const void*  maskp   = d_in[3];
  const float* attw    = (const float*)d_in[4];
  const float* memo    = (const float*)d_in[5];
  const float* geom    = (const float*)d_in[6];
  const float* Wq = (const float*)d_in[7];
  const float* bq = (const float*)d_in[8];
  const float* Wk = (const float*)d_in[9];
  const float* bk = (const float*)d_in[10];
  const float* Wv = (const float*)d_in[11];
  const float* bv = (const float*)d_in[12];
  const float* Wmm = (const float*)d_in[13];
  const float* bmm = (const float*)d_in[14];
  const float* Wo = (const float*)d_in[15];
  const float* bo = (const float*)d_in[16];

  char* ws = (char*)d_ws;
  size_t off = 0;
  auto alloc = [&](size_t bytes) {
    char* p = ws + off;
    off += (bytes + 255) & ~(size_t)255;
    return p;
  };
  const size_t MAT = (size_t)8192 * 512 * 2;  // 8 MiB fp16
  int* flag = (int*)alloc(256);
  _Float16* Wtq = (_Float16*)alloc((size_t)512 * 512 * 2);
  _Float16* Wtk = (_Float16*)alloc((size_t)512 * 512 * 2);
  _Float16* Wtv = (_Float16*)alloc((size_t)512 * 512 * 2);
  _Float16* Wto = (_Float16*)alloc((size_t)512 * 512 * 2);
  _Float16* Qp   = (_Float16*)alloc(MAT);
  _Float16* Kgp  = (_Float16*)alloc(MAT);
  _Float16* Vgtp = (_Float16*)alloc(MAT);
  _Float16* Ocat = (_Float16*)alloc(MAT);

  detect_mask_kernel<<<1, 256, 0, stream>>>((const unsigned int*)maskp, 4096, flag);
  wtrans_kernel<<<dim3(64, 4), 256, 0, stream>>>(Wq, Wk, Wv, Wo, Wtq, Wtk, Wtv, Wto);

  dim3 ggrid(64, 4);
  gemm_kernel<<<ggrid, 256, 0, stream>>>(queries, nullptr, Wtq, bq, nullptr, nullptr,
                                         nullptr, Qp, 0);
  gemm_kernel<<<ggrid, 256, 0, stream>>>(keys, nullptr, Wtk, bk, memo, Wmm, bmm, Kgp, 1);
  gemm_kernel<<<ggrid, 256, 0, stream>>>(values, nullptr, Wtv, bv, memo, Wmm, bmm,
                                         Vgtp, 2);

  attn_kernel<<<1024, 256, 0, stream>>>(Qp, Kgp, Vgtp, attw, geom, maskp, flag, Ocat);

  gemm_kernel<<<ggrid, 256, 0, stream>>>(nullptr, Ocat, Wto, bo, nullptr, nullptr,
                                         nullptr, d_out, 3);
}